// Round 10
// baseline (232.406 us; speedup 1.0000x reference)
//
#include <hip/hip_runtime.h>
#include <hip/hip_cooperative_groups.h>
#include <math.h>

namespace cg = cooperative_groups;

#define NB 4      // batch
#define LQ 128
#define LK 512
#define ET 128    // EMBED_TIME
#define NH 8
#define EKD 16    // EK = ET/NH
#define DD 64     // INPUT_DIM
#define HD 256    // HIDDEN_DIM

// workspace layout (floats)
#define QP_OFF 0                          // [512][128]
#define KP_OFF (NB*LQ*ET)                 // [2048][128]
#define CTX_OFF (KP_OFF + NB*LK*ET)       // [512][512]

// shared-memory region offsets (floats) within S[19200] (75.3 KB)
#define QS_B 10240                        // Qs[16][16]
#define ES_B 10496                        // Es[16][520]
#define PN_B 8256                         // phase-3 partials [4][16][64]

// Single cooperative kernel: phase1 proj (blocks 0..159) -> grid sync ->
// phase2 attention (all 256 blocks) -> grid sync -> phase3 outproj (0..127).
// Rationale: 3 dispatches -> 1 removes inter-dispatch gaps and keeps the
// proj outputs L2-warm for phase 2 (harness re-poisons a 256 MiB ws between
// iterations, sweeping L2+L3 -> kernels otherwise run cold).
__global__ __launch_bounds__(256) void fused_mta_kernel(
    const float* __restrict__ query, const float* __restrict__ key,
    const float* __restrict__ value, const int* __restrict__ mask,
    const float* __restrict__ Wq, const float* __restrict__ bq,
    const float* __restrict__ Wk, const float* __restrict__ bk,
    const float* __restrict__ Wo, const float* __restrict__ bo,
    float* __restrict__ ws, float* __restrict__ out)
{
  __shared__ __align__(16) float S[19200];
  cg::grid_group grid = cg::this_grid();
  const int bx  = blockIdx.x;
  const int tid = threadIdx.x;

  // ======================= Phase 1: Q/K projection =======================
  if (bx < 160) {
    const float* X; const float* W; const float* bias; float* outp; int rowbase;
    if (bx < 32) { X = query; W = Wq; bias = bq; outp = ws + QP_OFF; rowbase = bx * 16; }
    else         { X = key;   W = Wk; bias = bk; outp = ws + KP_OFF; rowbase = (bx - 32) * 16; }

    // Xs[16][132] (pad -> banks (r*4+kk)%32, conflict-free across r)
    for (int idx = tid; idx < 16 * 32; idx += 256) {
      int r = idx >> 5, c4 = idx & 31;
      *(float4*)(&S[r * 132 + c4 * 4]) =
          ((const float4*)(X + (size_t)(rowbase + r) * ET))[c4];
    }
    __syncthreads();

    const int r  = tid >> 4;
    const int c0 = (tid & 15) * 8;
    float acc[8] = {0.f,0.f,0.f,0.f,0.f,0.f,0.f,0.f};
    #pragma unroll 8
    for (int kk = 0; kk < ET; ++kk) {
      float x = S[r * 132 + kk];
      const float* wrow = W + (size_t)kk * ET + c0;
      float4 w0 = *(const float4*)(wrow);
      float4 w1 = *(const float4*)(wrow + 4);
      acc[0] = fmaf(x, w0.x, acc[0]);
      acc[1] = fmaf(x, w0.y, acc[1]);
      acc[2] = fmaf(x, w0.z, acc[2]);
      acc[3] = fmaf(x, w0.w, acc[3]);
      acc[4] = fmaf(x, w1.x, acc[4]);
      acc[5] = fmaf(x, w1.y, acc[5]);
      acc[6] = fmaf(x, w1.z, acc[6]);
      acc[7] = fmaf(x, w1.w, acc[7]);
    }
    float4 bb0 = *(const float4*)(bias + c0);
    float4 bb1 = *(const float4*)(bias + c0 + 4);
    float* orow = outp + (size_t)(rowbase + r) * ET + c0;
    *(float4*)(orow)     = make_float4(acc[0]+bb0.x, acc[1]+bb0.y, acc[2]+bb0.z, acc[3]+bb0.w);
    *(float4*)(orow + 4) = make_float4(acc[4]+bb1.x, acc[5]+bb1.y, acc[6]+bb1.z, acc[7]+bb1.w);
  }
  grid.sync();

  // ======================= Phase 2: attention =======================
  {
    const float* Qp = ws + QP_OFF;
    const float* Kp = ws + KP_OFF;
    float* ctx = ws + CTX_OFF;

    const int b  = bx >> 6;
    const int h  = (bx >> 3) & 7;
    const int qt = bx & 7;

    // stage K_h [512][16] into S stride 20; Q tile into S[QS_B]
    for (int idx = tid; idx < LK * 4; idx += 256) {
      int k = idx >> 2, j4 = idx & 3;
      float4 v4 = *(const float4*)(Kp + (size_t)(b * LK + k) * ET + h * EKD + j4 * 4);
      *(float4*)(&S[k * 20 + j4 * 4]) = v4;
    }
    if (tid < 64) {
      int r = tid >> 2, j4 = tid & 3;
      *(float4*)(&S[QS_B + r * 16 + j4 * 4]) =
          *(const float4*)(Qp + (size_t)(b * LQ + qt * 16 + r) * ET + h * EKD + j4 * 4);
    }
    __syncthreads();

    // ---- scores + rowmax + exp ----
    {
      const int r = tid >> 4;   // q row 0..15
      const int i = tid & 15;   // k sub-lane
      float qreg[16];
      #pragma unroll
      for (int j = 0; j < 16; ++j) qreg[j] = S[QS_B + r * 16 + j];

      float sv[32];
      float smax = -1e30f;
      #pragma unroll 4
      for (int kk = 0; kk < 32; ++kk) {
        int k = kk * 16 + i;
        const float* kp = &S[k * 20];
        float4 k0 = *(const float4*)(kp);
        float4 k1 = *(const float4*)(kp + 4);
        float4 k2 = *(const float4*)(kp + 8);
        float4 k3 = *(const float4*)(kp + 12);
        float dot = qreg[0] * k0.x;
        dot = fmaf(qreg[1],  k0.y, dot);
        dot = fmaf(qreg[2],  k0.z, dot);
        dot = fmaf(qreg[3],  k0.w, dot);
        dot = fmaf(qreg[4],  k1.x, dot);
        dot = fmaf(qreg[5],  k1.y, dot);
        dot = fmaf(qreg[6],  k1.z, dot);
        dot = fmaf(qreg[7],  k1.w, dot);
        dot = fmaf(qreg[8],  k2.x, dot);
        dot = fmaf(qreg[9],  k2.y, dot);
        dot = fmaf(qreg[10], k2.z, dot);
        dot = fmaf(qreg[11], k2.w, dot);
        dot = fmaf(qreg[12], k3.x, dot);
        dot = fmaf(qreg[13], k3.y, dot);
        dot = fmaf(qreg[14], k3.z, dot);
        dot = fmaf(qreg[15], k3.w, dot);
        float s = dot * 0.25f;   // 1/sqrt(EK)
        sv[kk] = s;
        smax = fmaxf(smax, s);
      }
      #pragma unroll
      for (int off = 1; off < 16; off <<= 1)
        smax = fmaxf(smax, __shfl_xor(smax, off));
      #pragma unroll
      for (int kk = 0; kk < 32; ++kk)
        S[ES_B + r * 520 + kk * 16 + i] = __expf(sv[kk] - smax);
    }
    __syncthreads();   // Es ready; Ks region dead -> partials reuse S[0..8191]

    // ---- Num/Den, wave-split over k ----
    {
      const int w = tid >> 6;
      const int d = tid & 63;
      float num[16], den[16];
      #pragma unroll
      for (int r = 0; r < 16; ++r) { num[r] = 0.f; den[r] = 0.f; }

      const int*   mcol = mask  + (size_t)b * LK * DD + d;
      const float* vcol = value + (size_t)b * LK * DD + d;
      const int kbase = w * 128;

      #pragma unroll 2
      for (int kb = 0; kb < 32; ++kb) {
        const int k = kbase + kb * 4;
        float m0 = (float)mcol[(size_t)(k + 0) * DD];
        float m1 = (float)mcol[(size_t)(k + 1) * DD];
        float m2 = (float)mcol[(size_t)(k + 2) * DD];
        float m3 = (float)mcol[(size_t)(k + 3) * DD];
        float v0 = vcol[(size_t)(k + 0) * DD];
        float v1 = vcol[(size_t)(k + 1) * DD];
        float v2 = vcol[(size_t)(k + 2) * DD];
        float v3 = vcol[(size_t)(k + 3) * DD];
        float mv0 = m0 * v0, mv1 = m1 * v1, mv2 = m2 * v2, mv3 = m3 * v3;
        #pragma unroll
        for (int r = 0; r < 16; ++r) {
          float4 e = *(const float4*)(&S[ES_B + r * 520 + k]);  // broadcast b128
          num[r] = fmaf(e.x, mv0, num[r]);
          num[r] = fmaf(e.y, mv1, num[r]);
          num[r] = fmaf(e.z, mv2, num[r]);
          num[r] = fmaf(e.w, mv3, num[r]);
          den[r] = fmaf(e.x, m0, den[r]);
          den[r] = fmaf(e.y, m1, den[r]);
          den[r] = fmaf(e.z, m2, den[r]);
          den[r] = fmaf(e.w, m3, den[r]);
        }
      }
      #pragma unroll
      for (int r = 0; r < 16; ++r) {
        S[(w * 16 + r) * 64 + d]        = num[r];
        S[4096 + (w * 16 + r) * 64 + d] = den[r];
      }
    }
    __syncthreads();

    // ---- cross-wave reduce + ctx write ----
    {
      const int d  = tid & 63;
      const int rg = tid >> 6;
      #pragma unroll
      for (int j = 0; j < 4; ++j) {
        const int r = rg * 4 + j;
        float n  = S[(r)      * 64 + d] + S[(16 + r) * 64 + d]
                 + S[(32 + r) * 64 + d] + S[(48 + r) * 64 + d];
        float dn = S[4096 + (r)      * 64 + d] + S[4096 + (16 + r) * 64 + d]
                 + S[4096 + (32 + r) * 64 + d] + S[4096 + (48 + r) * 64 + d];
        const int row = b * LQ + qt * 16 + r;
        ctx[(size_t)row * (NH * DD) + h * DD + d] = n / dn;
      }
    }
  }
  grid.sync();

  // ======================= Phase 3: out projection =======================
  if (bx < 128) {
    const float* ctx = ws + CTX_OFF;
    const int rt = bx >> 2;
    const int ct = bx & 3;
    const int r0 = rt * 16, c0 = ct * 64;

    // Cs[16][516] at S[0..]
    for (int idx = tid; idx < 16 * 128; idx += 256) {
      int r = idx >> 7, c4 = idx & 127;
      *(float4*)(&S[r * 516 + c4 * 4]) =
          *(const float4*)(ctx + (size_t)(r0 + r) * 512 + c4 * 4);
    }
    __syncthreads();

    const int w    = tid >> 6;
    const int lane = tid & 63;
    const int c    = c0 + lane;
    float acc[16];
    #pragma unroll
    for (int r = 0; r < 16; ++r) acc[r] = 0.f;

    const int kbase = w * 128;
    #pragma unroll 4
    for (int kb = 0; kb < 32; ++kb) {
      const int k = kbase + kb * 4;
      float w0 = Wo[(size_t)(k + 0) * HD + c];
      float w1 = Wo[(size_t)(k + 1) * HD + c];
      float w2 = Wo[(size_t)(k + 2) * HD + c];
      float w3 = Wo[(size_t)(k + 3) * HD + c];
      #pragma unroll
      for (int r = 0; r < 16; ++r) {
        float4 cs = *(const float4*)(&S[r * 516 + k]);   // broadcast b128
        acc[r] = fmaf(cs.x, w0, acc[r]);
        acc[r] = fmaf(cs.y, w1, acc[r]);
        acc[r] = fmaf(cs.z, w2, acc[r]);
        acc[r] = fmaf(cs.w, w3, acc[r]);
      }
    }
    #pragma unroll
    for (int r = 0; r < 16; ++r) S[PN_B + (w * 16 + r) * 64 + lane] = acc[r];
    __syncthreads();

    {
      const int rg = tid >> 6;
      const float bb = bo[c0 + (tid & 63)];
      #pragma unroll
      for (int j = 0; j < 4; ++j) {
        const int r = rg * 4 + j;
        float s = S[PN_B + (r)      * 64 + (tid & 63)]
                + S[PN_B + (16 + r) * 64 + (tid & 63)]
                + S[PN_B + (32 + r) * 64 + (tid & 63)]
                + S[PN_B + (48 + r) * 64 + (tid & 63)];
        out[(size_t)(r0 + r) * HD + c0 + (tid & 63)] = s + bb;
      }
    }
  }
}

// ---------------------------------------------------------------------------
extern "C" void kernel_launch(void* const* d_in, const int* in_sizes, int n_in,
                              void* d_out, int out_size, void* d_ws, size_t ws_size,
                              hipStream_t stream) {
  const float* query = (const float*)d_in[0];
  const float* key   = (const float*)d_in[1];
  const float* value = (const float*)d_in[2];
  const int*   mask  = (const int*)d_in[3];
  const float* Wq    = (const float*)d_in[4];
  const float* bq    = (const float*)d_in[5];
  const float* Wk    = (const float*)d_in[6];
  const float* bk    = (const float*)d_in[7];
  const float* Wo    = (const float*)d_in[8];
  const float* bo    = (const float*)d_in[9];
  float* out = (float*)d_out;
  float* ws  = (float*)d_ws;

  void* kargs[] = {
    (void*)&query, (void*)&key, (void*)&value, (void*)&mask,
    (void*)&Wq, (void*)&bq, (void*)&Wk, (void*)&bk,
    (void*)&Wo, (void*)&bo, (void*)&ws, (void*)&out
  };
  hipLaunchCooperativeKernel((void*)fused_mta_kernel,
                             dim3(256), dim3(256), kargs, 0, stream);
}

// Round 11
// 113.975 us; speedup vs baseline: 2.0391x; 2.0391x over previous
//
#include <hip/hip_runtime.h>
#include <math.h>

#define NB 4      // batch
#define LQ 128
#define LK 512
#define ET 128    // EMBED_TIME
#define NH 8
#define EKD 16    // EK = ET/NH
#define DD 64     // INPUT_DIM
#define HD 256    // HIDDEN_DIM

// workspace layout (floats)
#define QP_OFF 0                            // [512][128] flat Q-proj
#define KPB_OFF (NB*LQ*ET)                  // blocked K: [b][h][512][16] = 262144
#define CTX_OFF (KPB_OFF + NB*NH*LK*EKD)    // [512][512]

// attn shared offsets (floats)
#define QS_B 10240                          // Qs[8][16]
#define ES_B 10496                          // Es[8][520]

// ---------------------------------------------------------------------------
// K1: Q = query@Wq + bq (flat) ; K = key@Wk + bk (blocked [b][h][512][16])
// 160 blocks x 256 thr; blocks 0..31 -> Q (512 rows), 32..159 -> K (2048 rows)
// ---------------------------------------------------------------------------
__global__ __launch_bounds__(256) void proj_kernel(
    const float* __restrict__ query, const float* __restrict__ key,
    const float* __restrict__ Wq, const float* __restrict__ bq,
    const float* __restrict__ Wk, const float* __restrict__ bk,
    float* __restrict__ ws)
{
  __shared__ float Xs[16][132];   // pad 4 -> conflict-free
  const int blk = blockIdx.x;
  const int tid = threadIdx.x;
  const bool isQ = (blk < 32);
  const float* X; const float* W; const float* bias; int rowbase;
  if (isQ) { X = query; W = Wq; bias = bq; rowbase = blk * 16; }
  else     { X = key;   W = Wk; bias = bk; rowbase = (blk - 32) * 16; }

  for (int idx = tid; idx < 16 * 32; idx += 256) {
    int r = idx >> 5, c4 = idx & 31;
    *(float4*)(&Xs[r][c4 * 4]) = ((const float4*)(X + (size_t)(rowbase + r) * ET))[c4];
  }
  __syncthreads();

  const int r  = tid >> 4;
  const int c0 = (tid & 15) * 8;
  float acc[8] = {0.f,0.f,0.f,0.f,0.f,0.f,0.f,0.f};
  #pragma unroll 8
  for (int kk = 0; kk < ET; ++kk) {
    float x = Xs[r][kk];
    const float* wrow = W + (size_t)kk * ET + c0;
    float4 w0 = *(const float4*)(wrow);
    float4 w1 = *(const float4*)(wrow + 4);
    acc[0] = fmaf(x, w0.x, acc[0]);
    acc[1] = fmaf(x, w0.y, acc[1]);
    acc[2] = fmaf(x, w0.z, acc[2]);
    acc[3] = fmaf(x, w0.w, acc[3]);
    acc[4] = fmaf(x, w1.x, acc[4]);
    acc[5] = fmaf(x, w1.y, acc[5]);
    acc[6] = fmaf(x, w1.z, acc[6]);
    acc[7] = fmaf(x, w1.w, acc[7]);
  }
  float4 bb0 = *(const float4*)(bias + c0);
  float4 bb1 = *(const float4*)(bias + c0 + 4);
  float4 o0 = make_float4(acc[0]+bb0.x, acc[1]+bb0.y, acc[2]+bb0.z, acc[3]+bb0.w);
  float4 o1 = make_float4(acc[4]+bb1.x, acc[5]+bb1.y, acc[6]+bb1.z, acc[7]+bb1.w);

  if (isQ) {
    float* orow = ws + QP_OFF + (size_t)(rowbase + r) * ET + c0;
    *(float4*)(orow)     = o0;
    *(float4*)(orow + 4) = o1;
  } else {
    const int row  = rowbase + r;          // 0..2047
    const int b    = row >> 9;
    const int krow = row & 511;
    const int h    = c0 >> 4;
    const int cin  = c0 & 15;              // 0 or 8
    float* dst = ws + KPB_OFF + ((size_t)(b * NH + h) * LK + krow) * EKD + cin;
    *(float4*)(dst)     = o0;
    *(float4*)(dst + 4) = o1;
  }
}

// ---------------------------------------------------------------------------
// K2: attention. 512 blocks x 256 thr; block = (b, h, qt of 8 q-rows).
// LDS 57.3 KB -> 2 blocks/CU (8 waves/CU). K staged via coalesced reads of
// the blocked layout. Num/Den wave-split over k (4 x 128), partials alias
// the dead Ks region.
// ---------------------------------------------------------------------------
__global__ __launch_bounds__(256) void attn_kernel(
    const float* __restrict__ value, const int* __restrict__ mask,
    float* __restrict__ ws)
{
  __shared__ __align__(16) float S[14656];
  const int bx  = blockIdx.x;
  const int tid = threadIdx.x;
  const int b  = bx >> 7;
  const int h  = (bx >> 4) & 7;
  const int qt = bx & 15;

  const float* Qp = ws + QP_OFF;
  const float* Kb = ws + KPB_OFF + (size_t)(b * NH + h) * LK * EKD;
  float* ctx = ws + CTX_OFF;

  // stage K_h [512][16] -> S stride 20 (fully coalesced source)
  for (int idx = tid; idx < 2048; idx += 256) {
    int k = idx >> 2, j4 = idx & 3;
    float4 v4 = *(const float4*)(Kb + (size_t)idx * 4);
    *(float4*)(&S[k * 20 + j4 * 4]) = v4;
  }
  // stage Q tile [8][16]
  if (tid < 32) {
    int r = tid >> 2, j4 = tid & 3;
    *(float4*)(&S[QS_B + r * 16 + j4 * 4]) =
        *(const float4*)(Qp + (size_t)(b * LQ + qt * 8 + r) * ET + h * EKD + j4 * 4);
  }
  __syncthreads();

  // ---- scores + rowmax + exp ----
  {
    const int r = tid >> 5;   // q row 0..7
    const int i = tid & 31;   // k sub-lane 0..31
    float qreg[16];
    #pragma unroll
    for (int j = 0; j < 16; ++j) qreg[j] = S[QS_B + r * 16 + j];

    float sv[16];
    float smax = -1e30f;
    #pragma unroll 4
    for (int kk = 0; kk < 16; ++kk) {
      int k = kk * 32 + i;
      const float* kp = &S[k * 20];
      float4 k0 = *(const float4*)(kp);
      float4 k1 = *(const float4*)(kp + 4);
      float4 k2 = *(const float4*)(kp + 8);
      float4 k3 = *(const float4*)(kp + 12);
      float dot = qreg[0] * k0.x;
      dot = fmaf(qreg[1],  k0.y, dot);
      dot = fmaf(qreg[2],  k0.z, dot);
      dot = fmaf(qreg[3],  k0.w, dot);
      dot = fmaf(qreg[4],  k1.x, dot);
      dot = fmaf(qreg[5],  k1.y, dot);
      dot = fmaf(qreg[6],  k1.z, dot);
      dot = fmaf(qreg[7],  k1.w, dot);
      dot = fmaf(qreg[8],  k2.x, dot);
      dot = fmaf(qreg[9],  k2.y, dot);
      dot = fmaf(qreg[10], k2.z, dot);
      dot = fmaf(qreg[11], k2.w, dot);
      dot = fmaf(qreg[12], k3.x, dot);
      dot = fmaf(qreg[13], k3.y, dot);
      dot = fmaf(qreg[14], k3.z, dot);
      dot = fmaf(qreg[15], k3.w, dot);
      float s = dot * 0.25f;   // 1/sqrt(EK)
      sv[kk] = s;
      smax = fmaxf(smax, s);
    }
    #pragma unroll
    for (int off = 1; off < 32; off <<= 1)
      smax = fmaxf(smax, __shfl_xor(smax, off));
    #pragma unroll
    for (int kk = 0; kk < 16; ++kk)
      S[ES_B + r * 520 + kk * 32 + i] = __expf(sv[kk] - smax);
  }
  __syncthreads();   // Es ready; Ks region dead -> partials reuse S[0..4095]

  // ---- Num/Den, wave-split over k ----
  {
    const int w = tid >> 6;
    const int d = tid & 63;
    float num[8], den[8];
    #pragma unroll
    for (int r = 0; r < 8; ++r) { num[r] = 0.f; den[r] = 0.f; }

    const int*   mcol = mask  + (size_t)b * LK * DD + d;
    const float* vcol = value + (size_t)b * LK * DD + d;
    const int kbase = w * 128;

    #pragma unroll 4
    for (int kb = 0; kb < 32; ++kb) {
      const int k = kbase + kb * 4;
      float m0 = (float)mcol[(size_t)(k + 0) * DD];
      float m1 = (float)mcol[(size_t)(k + 1) * DD];
      float m2 = (float)mcol[(size_t)(k + 2) * DD];
      float m3 = (float)mcol[(size_t)(k + 3) * DD];
      float v0 = vcol[(size_t)(k + 0) * DD];
      float v1 = vcol[(size_t)(k + 1) * DD];
      float v2 = vcol[(size_t)(k + 2) * DD];
      float v3 = vcol[(size_t)(k + 3) * DD];
      float mv0 = m0 * v0, mv1 = m1 * v1, mv2 = m2 * v2, mv3 = m3 * v3;
      #pragma unroll
      for (int r = 0; r < 8; ++r) {
        float4 e = *(const float4*)(&S[ES_B + r * 520 + k]);  // broadcast b128
        num[r] = fmaf(e.x, mv0, num[r]);
        num[r] = fmaf(e.y, mv1, num[r]);
        num[r] = fmaf(e.z, mv2, num[r]);
        num[r] = fmaf(e.w, mv3, num[r]);
        den[r] = fmaf(e.x, m0, den[r]);
        den[r] = fmaf(e.y, m1, den[r]);
        den[r] = fmaf(e.z, m2, den[r]);
        den[r] = fmaf(e.w, m3, den[r]);
      }
    }
    #pragma unroll
    for (int r = 0; r < 8; ++r) {
      S[(w * 8 + r) * 64 + d]        = num[r];
      S[2048 + (w * 8 + r) * 64 + d] = den[r];
    }
  }
  __syncthreads();

  // ---- cross-wave reduce + ctx write ----
  {
    const int d  = tid & 63;
    const int rg = tid >> 6;
    #pragma unroll
    for (int j = 0; j < 2; ++j) {
      const int r = rg * 2 + j;
      float n  = S[(r) * 64 + d]        + S[(8 + r) * 64 + d]
               + S[(16 + r) * 64 + d]   + S[(24 + r) * 64 + d];
      float dn = S[2048 + (r) * 64 + d] + S[2048 + (8 + r) * 64 + d]
               + S[2048 + (16 + r) * 64 + d] + S[2048 + (24 + r) * 64 + d];
      const int row = b * LQ + qt * 8 + r;
      ctx[(size_t)row * (NH * DD) + h * DD + d] = n / dn;
    }
  }
}

// ---------------------------------------------------------------------------
// K3: out = ctx @ Wo + bo. 256 blocks x 256 thr; block = 16 rows x 32 cols,
// wave-split over k (4 x 128). Every CU occupied.
// ---------------------------------------------------------------------------
__global__ __launch_bounds__(256) void outproj_kernel(
    const float* __restrict__ Wo, const float* __restrict__ bo,
    const float* __restrict__ ws, float* __restrict__ out)
{
  __shared__ __align__(16) float S[10304];  // Cs[16][516] at 0; Pn[4][16][32] at 8256
  const float* ctx = ws + CTX_OFF;
  const int bx = blockIdx.x;
  const int rt = bx >> 3;           // 0..31
  const int ct = bx & 7;            // 0..7
  const int r0 = rt * 16, c0 = ct * 32;
  const int tid = threadIdx.x;

  for (int idx = tid; idx < 16 * 128; idx += 256) {
    int r = idx >> 7, c4 = idx & 127;
    *(float4*)(&S[r * 516 + c4 * 4]) =
        *(const float4*)(ctx + (size_t)(r0 + r) * 512 + c4 * 4);
  }
  __syncthreads();

  const int w    = tid >> 6;        // wave 0..3 -> k slice
  const int lane = tid & 63;
  const int rh   = lane >> 5;       // row half 0/1
  const int cc   = lane & 31;
  const int c    = c0 + cc;
  float acc[8];
  #pragma unroll
  for (int r = 0; r < 8; ++r) acc[r] = 0.f;

  const int kbase = w * 128;
  #pragma unroll 4
  for (int kb = 0; kb < 32; ++kb) {
    const int k = kbase + kb * 4;
    float w0 = Wo[(size_t)(k + 0) * HD + c];
    float w1 = Wo[(size_t)(k + 1) * HD + c];
    float w2 = Wo[(size_t)(k + 2) * HD + c];
    float w3 = Wo[(size_t)(k + 3) * HD + c];
    #pragma unroll
    for (int r = 0; r < 8; ++r) {
      const int row = rh * 8 + r;
      float4 cs = *(const float4*)(&S[row * 516 + k]);   // 2-addr b128 (free)
      acc[r] = fmaf(cs.x, w0, acc[r]);
      acc[r] = fmaf(cs.y, w1, acc[r]);
      acc[r] = fmaf(cs.z, w2, acc[r]);
      acc[r] = fmaf(cs.w, w3, acc[r]);
    }
  }
  #pragma unroll
  for (int r = 0; r < 8; ++r)
    S[8256 + ((size_t)w * 16 + rh * 8 + r) * 32 + cc] = acc[r];
  __syncthreads();

  {
    const int row = tid >> 4;             // 0..15
    const int cc0 = (tid & 15) * 2;
    #pragma unroll
    for (int j = 0; j < 2; ++j) {
      const int ccj = cc0 + j;
      float s = S[8256 + (0 * 16 + row) * 32 + ccj]
              + S[8256 + (1 * 16 + row) * 32 + ccj]
              + S[8256 + (2 * 16 + row) * 32 + ccj]
              + S[8256 + (3 * 16 + row) * 32 + ccj];
      out[(size_t)(r0 + row) * HD + c0 + ccj] = s + bo[c0 + ccj];
    }
  }
}

// ---------------------------------------------------------------------------
extern "C" void kernel_launch(void* const* d_in, const int* in_sizes, int n_in,
                              void* d_out, int out_size, void* d_ws, size_t ws_size,
                              hipStream_t stream) {
  const float* query = (const float*)d_in[0];
  const float* key   = (const float*)d_in[1];
  const float* value = (const float*)d_in[2];
  const int*   mask  = (const int*)d_in[3];
  const float* Wq    = (const float*)d_in[4];
  const float* bq    = (const float*)d_in[5];
  const float* Wk    = (const float*)d_in[6];
  const float* bk    = (const float*)d_in[7];
  const float* Wo    = (const float*)d_in[8];
  const float* bo    = (const float*)d_in[9];
  float* out = (float*)d_out;
  float* ws  = (float*)d_ws;

  proj_kernel<<<160, 256, 0, stream>>>(query, key, Wq, bq, Wk, bk, ws);
  attn_kernel<<<512, 256, 0, stream>>>(value, mask, ws);
  outproj_kernel<<<256, 256, 0, stream>>>(Wo, bo, ws, out);
}

// Round 18
// 100.747 us; speedup vs baseline: 2.3068x; 1.1313x over previous
//
#include <hip/hip_runtime.h>
#include <math.h>

#define NB 4      // batch
#define LQ 128
#define LK 512
#define ET 128    // EMBED_TIME
#define NH 8
#define EKD 16    // EK = ET/NH
#define DD 64     // INPUT_DIM
#define HD 256    // HIDDEN_DIM

// workspace layout (floats)
#define QP_OFF 0                            // [512][128] flat Q-proj
#define KPB_OFF (NB*LQ*ET)                  // blocked K: [b][h][512][16]

// attn shared offsets (floats)
#define QS_B 10240                          // Qs[8][16]
#define ES_B 10496                          // Es[8][520]
#define CTX_B 4096                          // ctx_s[8][68] (aliases dead Ks region)

// ---------------------------------------------------------------------------
// K1: Q = query@Wq + bq (flat) ; K = key@Wk + bk (blocked [b][h][512][16]);
// blocks 320..335 initialize out with the bias (consumed by attn's atomics).
// 336 blocks x 256 thr; 0..63 -> Q (8 rows each), 64..319 -> K (8 rows each).
// ---------------------------------------------------------------------------
__global__ __launch_bounds__(256) void proj_kernel(
    const float* __restrict__ query, const float* __restrict__ key,
    const float* __restrict__ Wq, const float* __restrict__ bq,
    const float* __restrict__ Wk, const float* __restrict__ bk,
    const float* __restrict__ bo,
    float* __restrict__ ws, float* __restrict__ out)
{
  const int blk = blockIdx.x;
  const int tid = threadIdx.x;

  if (blk >= 320) {                  // ---- bias init: out[r][c] = bo[c] ----
    const int bi = blk - 320;        // 16 blocks x 32 rows
    for (int idx = tid; idx < 2048; idx += 256) {
      const int r  = idx >> 6;       // 0..31
      const int c4 = idx & 63;       // 0..63 -> cols c4*4
      float4 bb = *(const float4*)(bo + c4 * 4);
      *(float4*)(out + (size_t)(bi * 32 + r) * HD + c4 * 4) = bb;
    }
    return;
  }

  __shared__ float Xs[8][132];       // pad 4 -> conflict-free
  const bool isQ = (blk < 64);
  const float* X; const float* W; const float* bias; int rowbase;
  if (isQ) { X = query; W = Wq; bias = bq; rowbase = blk * 8; }
  else     { X = key;   W = Wk; bias = bk; rowbase = (blk - 64) * 8; }

  {                                  // stage 8 rows x 128 (1 float4/thread)
    const int r = tid >> 5, c4 = tid & 31;
    *(float4*)(&Xs[r][c4 * 4]) = ((const float4*)(X + (size_t)(rowbase + r) * ET))[c4];
  }
  __syncthreads();

  const int r  = tid >> 5;           // 0..7
  const int c0 = (tid & 31) * 4;     // 0..124
  float acc[4] = {0.f, 0.f, 0.f, 0.f};
  #pragma unroll 8
  for (int kk = 0; kk < ET; ++kk) {
    float x = Xs[r][kk];
    float4 w = *(const float4*)(W + (size_t)kk * ET + c0);
    acc[0] = fmaf(x, w.x, acc[0]);
    acc[1] = fmaf(x, w.y, acc[1]);
    acc[2] = fmaf(x, w.z, acc[2]);
    acc[3] = fmaf(x, w.w, acc[3]);
  }
  float4 bb = *(const float4*)(bias + c0);
  float4 o  = make_float4(acc[0]+bb.x, acc[1]+bb.y, acc[2]+bb.z, acc[3]+bb.w);

  if (isQ) {
    *(float4*)(ws + QP_OFF + (size_t)(rowbase + r) * ET + c0) = o;
  } else {
    const int row  = rowbase + r;    // 0..2047
    const int b    = row >> 9;
    const int krow = row & 511;
    const int h    = c0 >> 4;
    const int cin  = c0 & 15;        // 0,4,8,12
    *(float4*)(ws + KPB_OFF + ((size_t)(b * NH + h) * LK + krow) * EKD + cin) = o;
  }
}

// ---------------------------------------------------------------------------
// K2: fused attention + out-projection. 512 blocks x 256 thr;
// block = (b, h, qt of 8 q-rows). LDS 58.6 KB -> 2 blocks/CU.
// scores->exp (fp32) -> Num/Den wave-split-k -> ctx tile in LDS ->
// contract vs Wo h-slice -> atomicAdd into out (bias pre-added by proj).
// ---------------------------------------------------------------------------
__global__ __launch_bounds__(256) void attn_kernel(
    const float* __restrict__ value, const int* __restrict__ mask,
    const float* __restrict__ Wo,
    const float* __restrict__ ws, float* __restrict__ out)
{
  __shared__ __align__(16) float S[14656];
  const int bx  = blockIdx.x;
  const int tid = threadIdx.x;
  const int b  = bx >> 7;
  const int h  = (bx >> 4) & 7;
  const int qt = bx & 15;

  const float* Qp = ws + QP_OFF;
  const float* Kb = ws + KPB_OFF + (size_t)(b * NH + h) * LK * EKD;

  // stage K_h [512][16] -> S stride 20 (coalesced source)
  for (int idx = tid; idx < 2048; idx += 256) {
    int k = idx >> 2, j4 = idx & 3;
    float4 v4 = *(const float4*)(Kb + (size_t)idx * 4);
    *(float4*)(&S[k * 20 + j4 * 4]) = v4;
  }
  if (tid < 32) {
    int r = tid >> 2, j4 = tid & 3;
    *(float4*)(&S[QS_B + r * 16 + j4 * 4]) =
        *(const float4*)(Qp + (size_t)(b * LQ + qt * 8 + r) * ET + h * EKD + j4 * 4);
  }
  __syncthreads();

  // ---- scores + rowmax + exp ----
  {
    const int r = tid >> 5;   // q row 0..7
    const int i = tid & 31;   // k sub-lane 0..31
    float qreg[16];
    #pragma unroll
    for (int j = 0; j < 16; ++j) qreg[j] = S[QS_B + r * 16 + j];

    float sv[16];
    float smax = -1e30f;
    #pragma unroll 4
    for (int kk = 0; kk < 16; ++kk) {
      int k = kk * 32 + i;
      const float* kp = &S[k * 20];
      float4 k0 = *(const float4*)(kp);
      float4 k1 = *(const float4*)(kp + 4);
      float4 k2 = *(const float4*)(kp + 8);
      float4 k3 = *(const float4*)(kp + 12);
      float dot = qreg[0] * k0.x;
      dot = fmaf(qreg[1],  k0.y, dot);
      dot = fmaf(qreg[2],  k0.z, dot);
      dot = fmaf(qreg[3],  k0.w, dot);
      dot = fmaf(qreg[4],  k1.x, dot);
      dot = fmaf(qreg[5],  k1.y, dot);
      dot = fmaf(qreg[6],  k1.z, dot);
      dot = fmaf(qreg[7],  k1.w, dot);
      dot = fmaf(qreg[8],  k2.x, dot);
      dot = fmaf(qreg[9],  k2.y, dot);
      dot = fmaf(qreg[10], k2.z, dot);
      dot = fmaf(qreg[11], k2.w, dot);
      dot = fmaf(qreg[12], k3.x, dot);
      dot = fmaf(qreg[13], k3.y, dot);
      dot = fmaf(qreg[14], k3.z, dot);
      dot = fmaf(qreg[15], k3.w, dot);
      float s = dot * 0.25f;   // 1/sqrt(EK)
      sv[kk] = s;
      smax = fmaxf(smax, s);
    }
    #pragma unroll
    for (int off = 1; off < 32; off <<= 1)
      smax = fmaxf(smax, __shfl_xor(smax, off));
    #pragma unroll
    for (int kk = 0; kk < 16; ++kk)
      S[ES_B + r * 520 + kk * 32 + i] = __expf(sv[kk] - smax);
  }
  __syncthreads();   // Es ready; Ks region dead

  // ---- Num/Den, wave-split over k; partials alias S[0..4095] ----
  {
    const int w = tid >> 6;
    const int d = tid & 63;
    float num[8], den[8];
    #pragma unroll
    for (int r = 0; r < 8; ++r) { num[r] = 0.f; den[r] = 0.f; }

    const int*   mcol = mask  + (size_t)b * LK * DD + d;
    const float* vcol = value + (size_t)b * LK * DD + d;
    const int kbase = w * 128;

    #pragma unroll 4
    for (int kb = 0; kb < 32; ++kb) {
      const int k = kbase + kb * 4;
      float m0 = (float)mcol[(size_t)(k + 0) * DD];
      float m1 = (float)mcol[(size_t)(k + 1) * DD];
      float m2 = (float)mcol[(size_t)(k + 2) * DD];
      float m3 = (float)mcol[(size_t)(k + 3) * DD];
      float v0 = vcol[(size_t)(k + 0) * DD];
      float v1 = vcol[(size_t)(k + 1) * DD];
      float v2 = vcol[(size_t)(k + 2) * DD];
      float v3 = vcol[(size_t)(k + 3) * DD];
      float mv0 = m0 * v0, mv1 = m1 * v1, mv2 = m2 * v2, mv3 = m3 * v3;
      #pragma unroll
      for (int r = 0; r < 8; ++r) {
        float4 e = *(const float4*)(&S[ES_B + r * 520 + k]);  // broadcast b128
        num[r] = fmaf(e.x, mv0, num[r]);
        num[r] = fmaf(e.y, mv1, num[r]);
        num[r] = fmaf(e.z, mv2, num[r]);
        num[r] = fmaf(e.w, mv3, num[r]);
        den[r] = fmaf(e.x, m0, den[r]);
        den[r] = fmaf(e.y, m1, den[r]);
        den[r] = fmaf(e.z, m2, den[r]);
        den[r] = fmaf(e.w, m3, den[r]);
      }
    }
    #pragma unroll
    for (int r = 0; r < 8; ++r) {
      S[(w * 8 + r) * 64 + d]        = num[r];
      S[2048 + (w * 8 + r) * 64 + d] = den[r];
    }
  }
  __syncthreads();

  // ---- cross-wave reduce -> ctx_s[8][68] in LDS ----
  {
    const int d  = tid & 63;
    const int rg = tid >> 6;
    #pragma unroll
    for (int j = 0; j < 2; ++j) {
      const int r = rg * 2 + j;
      float n  = S[(r) * 64 + d]        + S[(8 + r) * 64 + d]
               + S[(16 + r) * 64 + d]   + S[(24 + r) * 64 + d];
      float dn = S[2048 + (r) * 64 + d] + S[2048 + (8 + r) * 64 + d]
               + S[2048 + (16 + r) * 64 + d] + S[2048 + (24 + r) * 64 + d];
      S[CTX_B + r * 68 + d] = n / dn;
    }
  }
  __syncthreads();

  // ---- contract ctx_s[8][64] with Wo[h*64 .. h*64+64][256], atomicAdd ----
  {
    const int c = tid;                               // 0..255 output col
    const float* wocol = Wo + (size_t)(h * DD) * HD + c;
    float acc[8];
    #pragma unroll
    for (int r = 0; r < 8; ++r) acc[r] = 0.f;

    #pragma unroll 4
    for (int d4 = 0; d4 < 16; ++d4) {
      const int d = d4 * 4;
      float w0 = wocol[(size_t)(d + 0) * HD];
      float w1 = wocol[(size_t)(d + 1) * HD];
      float w2 = wocol[(size_t)(d + 2) * HD];
      float w3 = wocol[(size_t)(d + 3) * HD];
      #pragma unroll
      for (int r = 0; r < 8; ++r) {
        float4 e = *(const float4*)(&S[CTX_B + r * 68 + d]);  // broadcast b128
        acc[r] = fmaf(e.x, w0, acc[r]);
        acc[r] = fmaf(e.y, w1, acc[r]);
        acc[r] = fmaf(e.z, w2, acc[r]);
        acc[r] = fmaf(e.w, w3, acc[r]);
      }
    }
    const int row0 = b * LQ + qt * 8;
    #pragma unroll
    for (int r = 0; r < 8; ++r)
      atomicAdd(out + (size_t)(row0 + r) * HD + c, acc[r]);
  }
}

// ---------------------------------------------------------------------------
extern "C" void kernel_launch(void* const* d_in, const int* in_sizes, int n_in,
                              void* d_out, int out_size, void* d_ws, size_t ws_size,
                              hipStream_t stream) {
  const float* query = (const float*)d_in[0];
  const float* key   = (const float*)d_in[1];
  const float* value = (const float*)d_in[2];
  const int*   mask  = (const int*)d_in[3];
  const float* Wq    = (const float*)d_in[4];
  const float* bq    = (const float*)d_in[5];
  const float* Wk    = (const float*)d_in[6];
  const float* bk    = (const float*)d_in[7];
  const float* Wo    = (const float*)d_in[8];
  const float* bo    = (const float*)d_in[9];
  float* out = (float*)d_out;
  float* ws  = (float*)d_ws;

  proj_kernel<<<336, 256, 0, stream>>>(query, key, Wq, bq, Wk, bk, bo, ws, out);
  attn_kernel<<<512, 256, 0, stream>>>(value, mask, Wo, ws, out);
}